// Round 6
// baseline (212.679 us; speedup 1.0000x reference)
//
#include <hip/hip_runtime.h>

typedef unsigned int u32;
typedef unsigned short u16;
typedef __attribute__((ext_vector_type(8))) short bf16x8;
typedef __attribute__((ext_vector_type(4))) float f32x4;

#define T_ 2048
#define HEADS 16
#define DH 64
#define NQ (2 * HEADS * T_ * DH)  // 4194304 elems per tensor

__device__ __forceinline__ u16 f2bf(float f) {
    union { float f; u32 u; } x; x.f = f;
    return (u16)((x.u + 0x7fffu + ((x.u >> 16) & 1u)) >> 16);
}
// packed f32x2 -> bf16x2 (RNE), single HW instruction
__device__ __forceinline__ u32 pkbf(float lo, float hi) {
    u32 r;
    asm("v_cvt_pk_bf16_f32 %0, %1, %2" : "=v"(r) : "v"(lo), "v"(hi));
    return r;
}
// DPP lane-swap within 16-lane rows
template<int C>
__device__ __forceinline__ float dppf(float x) {
    union { float f; int i; } a, r;
    a.f = x;
    r.i = __builtin_amdgcn_update_dpp(a.i, a.i, C, 0xF, 0xF, false);
    return r.f;
}
__device__ __forceinline__ float redmax16(float x) {
    x = fmaxf(x, dppf<0xB1>(x));    // xor 1
    x = fmaxf(x, dppf<0x4E>(x));    // xor 2
    x = fmaxf(x, dppf<0x141>(x));   // row_half_mirror -> xor 4
    x = fmaxf(x, dppf<0x140>(x));   // row_mirror      -> xor 8
    return x;
}
__device__ __forceinline__ float redsum16(float x) {
    x += dppf<0xB1>(x);
    x += dppf<0x4E>(x);
    x += dppf<0x141>(x);
    x += dppf<0x140>(x);
    return x;
}

// q pre-scaled by 1/sqrt(64) * log2(e) so softmax runs in exp2 domain
#define QSCALE 0.18033688011112042f

// ================= MFMA GEMM (B^T form): C[m][n] = sum_k A[m][k]*B[n][k] =================
// EPI 0: qkv epilogue — q,k as [B,H,T,D] bf16 (q scaled QSCALE), v TRANSPOSED as [B,H,D,T].
// EPI 1: proj epilogue (fp32 out + bias)
template<int EPI>
__global__ __launch_bounds__(256, 2) void gemm_bt(
    const void* __restrict__ Aop, const float* __restrict__ B,
    const float* __restrict__ bias,
    u16* __restrict__ q, u16* __restrict__ k, u16* __restrict__ vt,
    float* __restrict__ outF)
{
    constexpr bool ABF16 = (EPI == 1);
    constexpr int K = 1024;
    __shared__ __align__(16) char AsB[16384];
    __shared__ __align__(16) char BsB[16384];
    const int tid = threadIdx.x;
    const int l = tid & 63, li = l & 15, lg = l >> 4;
    const int w = tid >> 6, wm = w >> 1, wn = w & 1;
    const int m0 = blockIdx.y * 128, n0 = blockIdx.x * 128;

    int sr[4], sp[4];
    #pragma unroll
    for (int j = 0; j < 4; ++j) { const int s = tid + j * 256; sr[j] = s >> 3; sp[j] = s & 7; }

    f32x4 acc[4][4];
    #pragma unroll
    for (int i = 0; i < 4; ++i)
        #pragma unroll
        for (int j = 0; j < 4; ++j) acc[i][j] = (f32x4){0.f, 0.f, 0.f, 0.f};

    const float* Af = (const float*)Aop;
    const u16*   Ah = (const u16*)Aop;

    float4 ar[4][2];
    uint4  arh[4];
    float4 br[4][2];

    #pragma unroll
    for (int j = 0; j < 4; ++j) {
        if constexpr (ABF16) {
            arh[j] = *(const uint4*)(Ah + (m0 + sr[j]) * K + sp[j] * 8);
        } else {
            const float* p = Af + (m0 + sr[j]) * K + sp[j] * 8;
            ar[j][0] = *(const float4*)p; ar[j][1] = *(const float4*)(p + 4);
        }
        const float* pb = B + (n0 + sr[j]) * K + sp[j] * 8;
        br[j][0] = *(const float4*)pb; br[j][1] = *(const float4*)(pb + 4);
    }

    for (int kt = 0; kt < K; kt += 64) {
        __syncthreads();
        #pragma unroll
        for (int j = 0; j < 4; ++j) {
            const int off = sr[j] * 128 + ((sp[j] ^ (sr[j] & 7)) << 4);
            if constexpr (ABF16) {
                *(uint4*)&AsB[off] = arh[j];
            } else {
                uint4 t;
                t.x = pkbf(ar[j][0].x, ar[j][0].y); t.y = pkbf(ar[j][0].z, ar[j][0].w);
                t.z = pkbf(ar[j][1].x, ar[j][1].y); t.w = pkbf(ar[j][1].z, ar[j][1].w);
                *(uint4*)&AsB[off] = t;
            }
            uint4 tb;
            tb.x = pkbf(br[j][0].x, br[j][0].y); tb.y = pkbf(br[j][0].z, br[j][0].w);
            tb.z = pkbf(br[j][1].x, br[j][1].y); tb.w = pkbf(br[j][1].z, br[j][1].w);
            *(uint4*)&BsB[off] = tb;
        }
        __syncthreads();
        if (kt + 64 < K) {
            const int kn = kt + 64;
            #pragma unroll
            for (int j = 0; j < 4; ++j) {
                if constexpr (ABF16) {
                    arh[j] = *(const uint4*)(Ah + (m0 + sr[j]) * K + kn + sp[j] * 8);
                } else {
                    const float* p = Af + (m0 + sr[j]) * K + kn + sp[j] * 8;
                    ar[j][0] = *(const float4*)p; ar[j][1] = *(const float4*)(p + 4);
                }
                const float* pb = B + (n0 + sr[j]) * K + kn + sp[j] * 8;
                br[j][0] = *(const float4*)pb; br[j][1] = *(const float4*)(pb + 4);
            }
        }
        #pragma unroll
        for (int kc = 0; kc < 2; ++kc) {
            const int key = ((kc * 4 + lg) ^ (li & 7)) << 4;
            bf16x8 a[4], b[4];
            #pragma unroll
            for (int f = 0; f < 4; ++f)
                a[f] = *(const bf16x8*)&AsB[(wm * 64 + f * 16 + li) * 128 + key];
            #pragma unroll
            for (int f = 0; f < 4; ++f)
                b[f] = *(const bf16x8*)&BsB[(wn * 64 + f * 16 + li) * 128 + key];
            #pragma unroll
            for (int mi = 0; mi < 4; ++mi)
                #pragma unroll
                for (int ni = 0; ni < 4; ++ni)
                    acc[mi][ni] = __builtin_amdgcn_mfma_f32_16x16x32_bf16(a[mi], b[ni], acc[mi][ni], 0, 0, 0);
        }
    }

    const int mb = m0 + wm * 64;
    const int nb0 = n0 + wn * 64;
    if constexpr (EPI == 0) {
        const int part = n0 >> 10;
        if (part < 2) {
            u16* dst = (part == 0) ? q : k;
            const float scl = (part == 0) ? QSCALE : 1.0f;
            #pragma unroll
            for (int mi = 0; mi < 4; ++mi)
                #pragma unroll
                for (int r = 0; r < 4; ++r) {
                    const int m = mb + mi * 16 + lg * 4 + r;
                    const int bb = m >> 11, t = m & 2047;
                    #pragma unroll
                    for (int ni = 0; ni < 4; ++ni) {
                        const int n = nb0 + ni * 16 + li;
                        const int c = n & 1023;
                        const int h = c >> 6, d = c & 63;
                        const float val = (acc[mi][ni][r] + bias[n]) * scl;
                        dst[(((bb << 4) + h) * T_ + t) * DH + d] = f2bf(val);
                    }
                }
        } else {
            // V transposed: vt[((b*16+h)*64 + d)*2048 + t]; 4 consecutive t per store
            #pragma unroll
            for (int mi = 0; mi < 4; ++mi) {
                const int m = mb + mi * 16 + lg * 4;
                const int bb = m >> 11, t0 = m & 2047;
                #pragma unroll
                for (int ni = 0; ni < 4; ++ni) {
                    const int n = nb0 + ni * 16 + li;
                    const int c = n & 1023;
                    const int h = c >> 6, d = c & 63;
                    const float bz = bias[n];
                    u32 w0 = pkbf(acc[mi][ni][0] + bz, acc[mi][ni][1] + bz);
                    u32 w1 = pkbf(acc[mi][ni][2] + bz, acc[mi][ni][3] + bz);
                    *(uint2*)&vt[(((bb << 4) + h) * 64 + d) * (size_t)T_ + t0] = make_uint2(w0, w1);
                }
            }
        }
    } else {
        #pragma unroll
        for (int mi = 0; mi < 4; ++mi)
            #pragma unroll
            for (int r = 0; r < 4; ++r) {
                const int m = mb + mi * 16 + lg * 4 + r;
                #pragma unroll
                for (int ni = 0; ni < 4; ++ni) {
                    const int n = nb0 + ni * 16 + li;
                    outF[m * 1024 + n] = acc[mi][ni][r] + bias[n];
                }
            }
    }
}

// ---------------- MFMA flash attention v5: barrier-free, K/V direct from L2 ----------------
// 256 threads (4 waves), Q-tile 64 (wave w owns rows qt*64 + w*16 .. +16).
// Grid (32 bh, 32 slots): qt = slot&1 ? 31-(slot>>1) : slot>>1  (alternating long/short).
// No __syncthreads. K b-frags read from K [b,h,t,d]; V b-frags from Vt [b,h,d,t].
// Only P goes through per-wave LDS (same-wave DS ordering, no barrier needed).
// Softmax in exp2 domain (q pre-scaled by log2e/8); l-reduction deferred to epilogue.
__global__ __launch_bounds__(256) void flash_attn(
    const u16* __restrict__ Q, const u16* __restrict__ K,
    const u16* __restrict__ Vt, u16* __restrict__ Y)
{
    __shared__ __align__(16) char PsB[4][2048];

    const int bh = blockIdx.x;
    const int slot = blockIdx.y;
    const int qt = (slot & 1) ? (31 - (slot >> 1)) : (slot >> 1);
    const int tid = threadIdx.x;
    const int w  = tid >> 6;
    const int l  = tid & 63;
    const int li = l & 15, lg = l >> 4;
    const u16* Qb = Q  + (size_t)bh * (T_ * DH);
    const u16* Kb = K  + (size_t)bh * (T_ * DH);
    const u16* Vb = Vt + (size_t)bh * (T_ * DH);   // rows of length T_
    char* Pw = PsB[w];
    const int b = bh >> 4, h = bh & 15;
    const int rdkey = (li & 7) << 4;

    const int wq0 = qt * 64 + w * 16;
    const int nj = qt + 1;                  // active KV tiles for this wave's rows

    bf16x8 qa[2];
    {
        const int qrow = wq0 + li;
        qa[0] = *(const bf16x8*)(Qb + qrow * 64 + 0  + lg * 8);
        qa[1] = *(const bf16x8*)(Qb + qrow * 64 + 32 + lg * 8);
    }
    f32x4 o[4];
    #pragma unroll
    for (int nb = 0; nb < 4; ++nb) o[nb] = (f32x4){0.f, 0.f, 0.f, 0.f};
    float m_r[4], l_r[4];
    #pragma unroll
    for (int r = 0; r < 4; ++r) { m_r[r] = -INFINITY; l_r[r] = 0.f; }

    // per-lane fragment bases
    const u16* kbase = Kb + li * 64 + lg * 8;            // + j*4096 + f*1024 + c*32
    const u16* vbase = Vb + (size_t)li * T_ + lg * 8;    // + nb*16*T_ + j*64 + c*32

    for (int j = 0; j < nj; ++j) {
        // ---- K b-frags direct from global (16B/lane, full 64B lines) ----
        bf16x8 kb[4][2];
        #pragma unroll
        for (int f = 0; f < 4; ++f)
            #pragma unroll
            for (int c = 0; c < 2; ++c)
                kb[f][c] = *(const bf16x8*)(kbase + j * 4096 + f * 1024 + c * 32);
        // ---- S = Q.K^T ----
        f32x4 s[4];
        #pragma unroll
        for (int f = 0; f < 4; ++f) {
            s[f] = (f32x4){0.f, 0.f, 0.f, 0.f};
            #pragma unroll
            for (int c = 0; c < 2; ++c)
                s[f] = __builtin_amdgcn_mfma_f32_16x16x32_bf16(qa[c], kb[f][c], s[f], 0, 0, 0);
        }
        // ---- V b-frags issued early: latency hides under softmax ----
        bf16x8 vf[4][2];
        #pragma unroll
        for (int nb = 0; nb < 4; ++nb)
            #pragma unroll
            for (int c = 0; c < 2; ++c)
                vf[nb][c] = *(const bf16x8*)(vbase + (size_t)nb * 16 * T_ + j * 64 + c * 32);
        // ---- causal mask on the diagonal tile ----
        if (j == nj - 1) {
            #pragma unroll
            for (int f = 0; f < 4; ++f)
                #pragma unroll
                for (int r = 0; r < 4; ++r)
                    if (j * 64 + f * 16 + li > wq0 + lg * 4 + r) s[f][r] = -INFINITY;
        }
        // ---- online softmax (exp2 domain), l-sum deferred ----
        #pragma unroll
        for (int r = 0; r < 4; ++r) {
            float tm = fmaxf(fmaxf(s[0][r], s[1][r]), fmaxf(s[2][r], s[3][r]));
            tm = redmax16(tm);
            const float mnew = fmaxf(m_r[r], tm);
            const float corr = exp2f(m_r[r] - mnew);
            m_r[r] = mnew;
            float a = 0.f;
            #pragma unroll
            for (int f = 0; f < 4; ++f) {
                const float p = exp2f(s[f][r] - mnew);
                s[f][r] = p;
                a += p;
            }
            l_r[r] = l_r[r] * corr + a;     // per-lane partial; reduced at epilogue
            #pragma unroll
            for (int nb = 0; nb < 4; ++nb) o[nb][r] *= corr;
        }
        // ---- P -> per-wave LDS (swizzled), read back as A-frags ----
        #pragma unroll
        for (int r = 0; r < 4; ++r) {
            const int row = lg * 4 + r;
            const int rkey = (row & 7) << 4;
            const u32 pk0 = pkbf(s[0][r], s[1][r]);
            const u32 pk1 = pkbf(s[2][r], s[3][r]);
            *(u16*)&Pw[row * 128 + (((     li) * 2) ^ rkey)] = (u16)pk0;
            *(u16*)&Pw[row * 128 + (((16 + li) * 2) ^ rkey)] = (u16)(pk0 >> 16);
            *(u16*)&Pw[row * 128 + (((32 + li) * 2) ^ rkey)] = (u16)pk1;
            *(u16*)&Pw[row * 128 + (((48 + li) * 2) ^ rkey)] = (u16)(pk1 >> 16);
        }
        // ---- O += P @ V ----
        #pragma unroll
        for (int c = 0; c < 2; ++c) {
            bf16x8 pa = *(const bf16x8*)&Pw[li * 128 + ((c * 64 + lg * 16) ^ rdkey)];
            #pragma unroll
            for (int nb = 0; nb < 4; ++nb)
                o[nb] = __builtin_amdgcn_mfma_f32_16x16x32_bf16(pa, vf[nb][c], o[nb], 0, 0, 0);
        }
    }

    // ---- epilogue: reduce l, normalize, write Y in [B,T,C] ----
    #pragma unroll
    for (int r = 0; r < 4; ++r) {
        const float inv = 1.0f / redsum16(l_r[r]);
        const int row = wq0 + lg * 4 + r;
        u16* yp = Y + ((size_t)(b * T_ + row) * 1024) + h * DH + li;
        #pragma unroll
        for (int nb = 0; nb < 4; ++nb)
            yp[nb * 16] = f2bf(o[nb][r] * inv);
    }
}

extern "C" void kernel_launch(void* const* d_in, const int* in_sizes, int n_in,
                              void* d_out, int out_size, void* d_ws, size_t ws_size,
                              hipStream_t stream) {
    const float* x      = (const float*)d_in[0];
    const float* W_attn = (const float*)d_in[1];
    const float* b_attn = (const float*)d_in[2];
    const float* W_proj = (const float*)d_in[3];
    const float* b_proj = (const float*)d_in[4];
    float* out = (float*)d_out;

    u16* q  = (u16*)d_ws;      // [B,H,T,D]  (scaled by log2e/8)
    u16* k  = q + NQ;          // [B,H,T,D]
    u16* vt = k + NQ;          // [B,H,D,T]  (transposed)
    u16* y  = vt + NQ;         // [B,T,C]

    gemm_bt<0><<<dim3(24, 32), 256, 0, stream>>>(x, W_attn, b_attn, q, k, vt, nullptr);
    flash_attn<<<dim3(32, 32), 256, 0, stream>>>(q, k, vt, y);
    gemm_bt<1><<<dim3(8, 32), 256, 0, stream>>>(y, W_proj, b_proj, nullptr, nullptr, nullptr, out);
}

// Round 7
// 173.140 us; speedup vs baseline: 1.2284x; 1.2284x over previous
//
#include <hip/hip_runtime.h>

typedef unsigned int u32;
typedef unsigned short u16;
typedef __attribute__((ext_vector_type(8))) short bf16x8;
typedef __attribute__((ext_vector_type(4))) float f32x4;

#define T_ 2048
#define HEADS 16
#define DH 64
#define NQ (2 * HEADS * T_ * DH)  // 4194304 elems per tensor

__device__ __forceinline__ u16 f2bf(float f) {
    union { float f; u32 u; } x; x.f = f;
    return (u16)((x.u + 0x7fffu + ((x.u >> 16) & 1u)) >> 16);
}
// packed f32x2 -> bf16x2 (RNE), single HW instruction
__device__ __forceinline__ u32 pkbf(float lo, float hi) {
    u32 r;
    asm("v_cvt_pk_bf16_f32 %0, %1, %2" : "=v"(r) : "v"(lo), "v"(hi));
    return r;
}
// DPP lane-swap within 16-lane rows
template<int C>
__device__ __forceinline__ float dppf(float x) {
    union { float f; int i; } a, r;
    a.f = x;
    r.i = __builtin_amdgcn_update_dpp(a.i, a.i, C, 0xF, 0xF, false);
    return r.f;
}
__device__ __forceinline__ float redmax16(float x) {
    x = fmaxf(x, dppf<0xB1>(x));    // xor 1
    x = fmaxf(x, dppf<0x4E>(x));    // xor 2
    x = fmaxf(x, dppf<0x141>(x));   // row_half_mirror -> xor 4
    x = fmaxf(x, dppf<0x140>(x));   // row_mirror      -> xor 8
    return x;
}
__device__ __forceinline__ float redsum16(float x) {
    x += dppf<0xB1>(x);
    x += dppf<0x4E>(x);
    x += dppf<0x141>(x);
    x += dppf<0x140>(x);
    return x;
}

// q pre-scaled by 1/sqrt(64) * log2(e) so softmax runs in exp2 domain
#define QSCALE 0.18033688011112042f

// ================= MFMA GEMM (B^T form): C[m][n] = sum_k A[m][k]*B[n][k] =================
// EPI 0: qkv epilogue — q,k as [B,H,T,D] bf16 (q scaled QSCALE), v TRANSPOSED as [B,H,D,T].
// EPI 1: proj epilogue (fp32 out + bias)
template<int EPI>
__global__ __launch_bounds__(256, 2) void gemm_bt(
    const void* __restrict__ Aop, const float* __restrict__ B,
    const float* __restrict__ bias,
    u16* __restrict__ q, u16* __restrict__ k, u16* __restrict__ vt,
    float* __restrict__ outF)
{
    constexpr bool ABF16 = (EPI == 1);
    constexpr int K = 1024;
    __shared__ __align__(16) char AsB[16384];
    __shared__ __align__(16) char BsB[16384];
    const int tid = threadIdx.x;
    const int l = tid & 63, li = l & 15, lg = l >> 4;
    const int w = tid >> 6, wm = w >> 1, wn = w & 1;
    const int m0 = blockIdx.y * 128, n0 = blockIdx.x * 128;

    int sr[4], sp[4];
    #pragma unroll
    for (int j = 0; j < 4; ++j) { const int s = tid + j * 256; sr[j] = s >> 3; sp[j] = s & 7; }

    f32x4 acc[4][4];
    #pragma unroll
    for (int i = 0; i < 4; ++i)
        #pragma unroll
        for (int j = 0; j < 4; ++j) acc[i][j] = (f32x4){0.f, 0.f, 0.f, 0.f};

    const float* Af = (const float*)Aop;
    const u16*   Ah = (const u16*)Aop;

    float4 ar[4][2];
    uint4  arh[4];
    float4 br[4][2];

    #pragma unroll
    for (int j = 0; j < 4; ++j) {
        if constexpr (ABF16) {
            arh[j] = *(const uint4*)(Ah + (m0 + sr[j]) * K + sp[j] * 8);
        } else {
            const float* p = Af + (m0 + sr[j]) * K + sp[j] * 8;
            ar[j][0] = *(const float4*)p; ar[j][1] = *(const float4*)(p + 4);
        }
        const float* pb = B + (n0 + sr[j]) * K + sp[j] * 8;
        br[j][0] = *(const float4*)pb; br[j][1] = *(const float4*)(pb + 4);
    }

    for (int kt = 0; kt < K; kt += 64) {
        __syncthreads();
        #pragma unroll
        for (int j = 0; j < 4; ++j) {
            const int off = sr[j] * 128 + ((sp[j] ^ (sr[j] & 7)) << 4);
            if constexpr (ABF16) {
                *(uint4*)&AsB[off] = arh[j];
            } else {
                uint4 t;
                t.x = pkbf(ar[j][0].x, ar[j][0].y); t.y = pkbf(ar[j][0].z, ar[j][0].w);
                t.z = pkbf(ar[j][1].x, ar[j][1].y); t.w = pkbf(ar[j][1].z, ar[j][1].w);
                *(uint4*)&AsB[off] = t;
            }
            uint4 tb;
            tb.x = pkbf(br[j][0].x, br[j][0].y); tb.y = pkbf(br[j][0].z, br[j][0].w);
            tb.z = pkbf(br[j][1].x, br[j][1].y); tb.w = pkbf(br[j][1].z, br[j][1].w);
            *(uint4*)&BsB[off] = tb;
        }
        __syncthreads();
        if (kt + 64 < K) {
            const int kn = kt + 64;
            #pragma unroll
            for (int j = 0; j < 4; ++j) {
                if constexpr (ABF16) {
                    arh[j] = *(const uint4*)(Ah + (m0 + sr[j]) * K + kn + sp[j] * 8);
                } else {
                    const float* p = Af + (m0 + sr[j]) * K + kn + sp[j] * 8;
                    ar[j][0] = *(const float4*)p; ar[j][1] = *(const float4*)(p + 4);
                }
                const float* pb = B + (n0 + sr[j]) * K + kn + sp[j] * 8;
                br[j][0] = *(const float4*)pb; br[j][1] = *(const float4*)(pb + 4);
            }
        }
        #pragma unroll
        for (int kc = 0; kc < 2; ++kc) {
            const int key = ((kc * 4 + lg) ^ (li & 7)) << 4;
            bf16x8 a[4], b[4];
            #pragma unroll
            for (int f = 0; f < 4; ++f)
                a[f] = *(const bf16x8*)&AsB[(wm * 64 + f * 16 + li) * 128 + key];
            #pragma unroll
            for (int f = 0; f < 4; ++f)
                b[f] = *(const bf16x8*)&BsB[(wn * 64 + f * 16 + li) * 128 + key];
            #pragma unroll
            for (int mi = 0; mi < 4; ++mi)
                #pragma unroll
                for (int ni = 0; ni < 4; ++ni)
                    acc[mi][ni] = __builtin_amdgcn_mfma_f32_16x16x32_bf16(a[mi], b[ni], acc[mi][ni], 0, 0, 0);
        }
    }

    const int mb = m0 + wm * 64;
    const int nb0 = n0 + wn * 64;
    if constexpr (EPI == 0) {
        const int part = n0 >> 10;
        if (part < 2) {
            u16* dst = (part == 0) ? q : k;
            const float scl = (part == 0) ? QSCALE : 1.0f;
            #pragma unroll
            for (int mi = 0; mi < 4; ++mi)
                #pragma unroll
                for (int r = 0; r < 4; ++r) {
                    const int m = mb + mi * 16 + lg * 4 + r;
                    const int bb = m >> 11, t = m & 2047;
                    #pragma unroll
                    for (int ni = 0; ni < 4; ++ni) {
                        const int n = nb0 + ni * 16 + li;
                        const int c = n & 1023;
                        const int h = c >> 6, d = c & 63;
                        const float val = (acc[mi][ni][r] + bias[n]) * scl;
                        dst[(((bb << 4) + h) * T_ + t) * DH + d] = f2bf(val);
                    }
                }
        } else {
            // V transposed: vt[((b*16+h)*64 + d)*2048 + t]; 4 consecutive t per store
            #pragma unroll
            for (int mi = 0; mi < 4; ++mi) {
                const int m = mb + mi * 16 + lg * 4;
                const int bb = m >> 11, t0 = m & 2047;
                #pragma unroll
                for (int ni = 0; ni < 4; ++ni) {
                    const int n = nb0 + ni * 16 + li;
                    const int c = n & 1023;
                    const int h = c >> 6, d = c & 63;
                    const float bz = bias[n];
                    u32 w0 = pkbf(acc[mi][ni][0] + bz, acc[mi][ni][1] + bz);
                    u32 w1 = pkbf(acc[mi][ni][2] + bz, acc[mi][ni][3] + bz);
                    *(uint2*)&vt[(((bb << 4) + h) * 64 + d) * (size_t)T_ + t0] = make_uint2(w0, w1);
                }
            }
        }
    } else {
        #pragma unroll
        for (int mi = 0; mi < 4; ++mi)
            #pragma unroll
            for (int r = 0; r < 4; ++r) {
                const int m = mb + mi * 16 + lg * 4 + r;
                #pragma unroll
                for (int ni = 0; ni < 4; ++ni) {
                    const int n = nb0 + ni * 16 + li;
                    outF[m * 1024 + n] = acc[mi][ni][r] + bias[n];
                }
            }
    }
}

// ---------------- MFMA flash attention v7 ----------------
// 256 threads (4 waves). Q-tile 64 (wave w owns rows qt*64+w*16..+16). KV tile 128.
// Grid (32 bh, 16 pairs): block does q-tiles {pr, 31-pr} -> exactly 17 KV-128 steps. 2 blocks/CU.
// K LDS [128t][64d] swizzled; V LDS 2 half-tiles [64d][64t] swizzled (from pre-transposed Vt);
// P per-wave 2 half-tiles [16][64]. Double-buffered K/V, 1 barrier per KV-128 step.
// exp2-domain softmax (q pre-scaled), DPP reductions, deferred l-sum, setprio on MFMA.
__global__ __launch_bounds__(256, 2) void flash_attn(
    const u16* __restrict__ Q, const u16* __restrict__ K,
    const u16* __restrict__ Vt, u16* __restrict__ Y)
{
    __shared__ __align__(16) char KsB[2][16384];
    __shared__ __align__(16) char VsB[2][16384];   // [dbuf][half*8192 + d*128 + swz]
    __shared__ __align__(16) char PsB[4][4096];    // [wave][half*2048 + row*128 + swz]

    const int bh = blockIdx.x;
    const int pr = blockIdx.y;
    const int tid = threadIdx.x;
    const int w = tid >> 6, l = tid & 63;
    const int li = l & 15, lg = l >> 4;
    const u16* Qb = Q  + (size_t)bh * (T_ * DH);
    const u16* Kb = K  + (size_t)bh * (T_ * DH);
    const u16* Vb = Vt + (size_t)bh * (T_ * DH);   // rows (d) of length T_
    char* Pw = PsB[w];
    const int b = bh >> 4, h = bh & 15;
    const int rdkey = (li & 7) << 4;

    // staging maps (derived conflict-free: <=2 lanes/bank on write and read)
    const int krow = tid >> 1, ks0 = (tid & 1) * 4;   // K: 128 rows x 8 segs
    const int kkey = (krow & 7) << 4;
    const int vrow = tid >> 2, vs0 = tid & 3;         // V half: 64 rows x 8 segs
    const int vkey = (vrow & 7) << 4;

    #pragma unroll
    for (int ph = 0; ph < 2; ++ph) {
        const int qt = ph ? (31 - pr) : pr;
        const int wq0 = qt * 64 + w * 16;
        const int n128 = (qt >> 1) + 1;

        bf16x8 qa[2];
        {
            const int qrow = wq0 + li;
            qa[0] = *(const bf16x8*)(Qb + qrow * 64 + 0  + lg * 8);
            qa[1] = *(const bf16x8*)(Qb + qrow * 64 + 32 + lg * 8);
        }
        f32x4 o[4];
        #pragma unroll
        for (int nb = 0; nb < 4; ++nb) o[nb] = (f32x4){0.f, 0.f, 0.f, 0.f};
        float m_r[4], l_r[4];
        #pragma unroll
        for (int r = 0; r < 4; ++r) { m_r[r] = -INFINITY; l_r[r] = 0.f; }

        uint4 kr[4], vr[4];
        // ---- prologue: stage tile 0 into buf 0 ----
        #pragma unroll
        for (int c = 0; c < 4; ++c)
            kr[c] = *(const uint4*)(Kb + krow * 64 + (ks0 + c) * 8);
        #pragma unroll
        for (int c = 0; c < 4; ++c)
            vr[c] = *(const uint4*)(Vb + (size_t)vrow * T_ + (c >> 1) * 64 + (vs0 + (c & 1) * 4) * 8);
        // (safe without a barrier here: the previous phase's final iteration ends in
        //  __syncthreads() after all LDS reads; first phase has no prior LDS use)
        #pragma unroll
        for (int c = 0; c < 4; ++c)
            *(uint4*)&KsB[0][krow * 128 + (((ks0 + c) << 4) ^ kkey)] = kr[c];
        #pragma unroll
        for (int c = 0; c < 4; ++c)
            *(uint4*)&VsB[0][(c >> 1) * 8192 + vrow * 128 + (((vs0 + (c & 1) * 4) << 4) ^ vkey)] = vr[c];
        __syncthreads();

        for (int j = 0; j < n128; ++j) {
            const int cur = j & 1;
            const bool nxt = (j + 1 < n128);
            // ---- issue next tile's global loads (hide under compute) ----
            if (nxt) {
                const int t0 = (j + 1) << 7;
                #pragma unroll
                for (int c = 0; c < 4; ++c)
                    kr[c] = *(const uint4*)(Kb + (t0 + krow) * 64 + (ks0 + c) * 8);
                #pragma unroll
                for (int c = 0; c < 4; ++c)
                    vr[c] = *(const uint4*)(Vb + (size_t)vrow * T_ + t0 + (c >> 1) * 64 + (vs0 + (c & 1) * 4) * 8);
            }
            // ---- S = Q.K^T over 128 k-cols ----
            const char* Kc = KsB[cur];
            f32x4 s[8];
            __builtin_amdgcn_s_setprio(1);
            #pragma unroll
            for (int f = 0; f < 8; ++f) {
                s[f] = (f32x4){0.f, 0.f, 0.f, 0.f};
                #pragma unroll
                for (int c = 0; c < 2; ++c) {
                    bf16x8 kb = *(const bf16x8*)&Kc[(f * 16 + li) * 128 + ((c * 64 + lg * 16) ^ rdkey)];
                    s[f] = __builtin_amdgcn_mfma_f32_16x16x32_bf16(qa[c], kb, s[f], 0, 0, 0);
                }
            }
            __builtin_amdgcn_s_setprio(0);
            // ---- causal mask (only when this tile can exceed the diagonal) ----
            if ((j << 7) + 127 > wq0) {
                #pragma unroll
                for (int f = 0; f < 8; ++f)
                    #pragma unroll
                    for (int r = 0; r < 4; ++r)
                        if ((j << 7) + f * 16 + li > wq0 + lg * 4 + r) s[f][r] = -INFINITY;
            }
            // ---- online softmax (exp2), deferred l-sum ----
            #pragma unroll
            for (int r = 0; r < 4; ++r) {
                float tm = fmaxf(fmaxf(fmaxf(s[0][r], s[1][r]), fmaxf(s[2][r], s[3][r])),
                                 fmaxf(fmaxf(s[4][r], s[5][r]), fmaxf(s[6][r], s[7][r])));
                tm = redmax16(tm);
                const float mnew = fmaxf(m_r[r], tm);
                const float corr = exp2f(m_r[r] - mnew);
                m_r[r] = mnew;
                float a = 0.f;
                #pragma unroll
                for (int f = 0; f < 8; ++f) {
                    const float p = exp2f(s[f][r] - mnew);
                    s[f][r] = p;
                    a += p;
                }
                l_r[r] = l_r[r] * corr + a;
                #pragma unroll
                for (int nb = 0; nb < 4; ++nb) o[nb][r] *= corr;
            }
            // ---- P -> per-wave LDS (2 half-tiles) ----
            #pragma unroll
            for (int r = 0; r < 4; ++r) {
                const int row = lg * 4 + r;
                const int rkey = (row & 7) << 4;
                #pragma unroll
                for (int pp = 0; pp < 4; ++pp) {
                    const u32 pk = pkbf(s[2 * pp][r], s[2 * pp + 1][r]);
                    const int half = pp >> 1;
                    const int c0 = ((2 * pp) & 3) * 16 + li;      // col of f=2pp within half
                    char* Ph = Pw + half * 2048 + row * 128;
                    *(u16*)&Ph[((c0)      * 2) ^ rkey] = (u16)pk;
                    *(u16*)&Ph[((c0 + 16) * 2) ^ rkey] = (u16)(pk >> 16);
                }
            }
            // ---- write prefetched K/V into the other buffer ----
            if (nxt) {
                #pragma unroll
                for (int c = 0; c < 4; ++c)
                    *(uint4*)&KsB[cur ^ 1][krow * 128 + (((ks0 + c) << 4) ^ kkey)] = kr[c];
                #pragma unroll
                for (int c = 0; c < 4; ++c)
                    *(uint4*)&VsB[cur ^ 1][(c >> 1) * 8192 + vrow * 128 + (((vs0 + (c & 1) * 4) << 4) ^ vkey)] = vr[c];
            }
            // ---- O += P @ V ----
            const char* Vc = VsB[cur];
            __builtin_amdgcn_s_setprio(1);
            #pragma unroll
            for (int c = 0; c < 4; ++c) {
                const int half = c >> 1;
                const int cb = (c & 1) * 64 + lg * 16;
                bf16x8 pa = *(const bf16x8*)&Pw[half * 2048 + li * 128 + (cb ^ rdkey)];
                #pragma unroll
                for (int nb = 0; nb < 4; ++nb) {
                    bf16x8 vb = *(const bf16x8*)&Vc[half * 8192 + (nb * 16 + li) * 128 + (cb ^ rdkey)];
                    o[nb] = __builtin_amdgcn_mfma_f32_16x16x32_bf16(pa, vb, o[nb], 0, 0, 0);
                }
            }
            __builtin_amdgcn_s_setprio(0);
            __syncthreads();
        }

        // ---- epilogue: reduce l, normalize, write Y in [B,T,C] ----
        #pragma unroll
        for (int r = 0; r < 4; ++r) {
            const float inv = 1.0f / redsum16(l_r[r]);
            const int row = wq0 + lg * 4 + r;
            u16* yp = Y + ((size_t)(b * T_ + row) * 1024) + h * DH + li;
            #pragma unroll
            for (int nb = 0; nb < 4; ++nb)
                yp[nb * 16] = f2bf(o[nb][r] * inv);
        }
    }
}

extern "C" void kernel_launch(void* const* d_in, const int* in_sizes, int n_in,
                              void* d_out, int out_size, void* d_ws, size_t ws_size,
                              hipStream_t stream) {
    const float* x      = (const float*)d_in[0];
    const float* W_attn = (const float*)d_in[1];
    const float* b_attn = (const float*)d_in[2];
    const float* W_proj = (const float*)d_in[3];
    const float* b_proj = (const float*)d_in[4];
    float* out = (float*)d_out;

    u16* q  = (u16*)d_ws;      // [B,H,T,D]  (scaled by log2e/8)
    u16* k  = q + NQ;          // [B,H,T,D]
    u16* vt = k + NQ;          // [B,H,D,T]  (transposed)
    u16* y  = vt + NQ;         // [B,T,C]

    gemm_bt<0><<<dim3(24, 32), 256, 0, stream>>>(x, W_attn, b_attn, q, k, vt, nullptr);
    flash_attn<<<dim3(32, 16), 256, 0, stream>>>(q, k, vt, y);
    gemm_bt<1><<<dim3(8, 32), 256, 0, stream>>>(y, W_proj, b_proj, nullptr, nullptr, nullptr, out);
}

// Round 8
// 141.657 us; speedup vs baseline: 1.5014x; 1.2223x over previous
//
#include <hip/hip_runtime.h>

typedef unsigned int u32;
typedef unsigned short u16;
typedef __attribute__((ext_vector_type(8))) short bf16x8;
typedef __attribute__((ext_vector_type(4))) float f32x4;

#define T_ 2048
#define HEADS 16
#define DH 64
#define NQ (2 * HEADS * T_ * DH)  // 4194304 elems per tensor

__device__ __forceinline__ u16 f2bf(float f) {
    union { float f; u32 u; } x; x.f = f;
    return (u16)((x.u + 0x7fffu + ((x.u >> 16) & 1u)) >> 16);
}
// packed f32x2 -> bf16x2 (RNE), single HW instruction
__device__ __forceinline__ u32 pkbf(float lo, float hi) {
    u32 r;
    asm("v_cvt_pk_bf16_f32 %0, %1, %2" : "=v"(r) : "v"(lo), "v"(hi));
    return r;
}
// async global->LDS, 16B per lane: LDS dest = wave-uniform base + lane*16
__device__ __forceinline__ void gll16(const void* g, void* l) {
    __builtin_amdgcn_global_load_lds(
        (const __attribute__((address_space(1))) void*)g,
        (__attribute__((address_space(3))) void*)l, 16, 0, 0);
}
// DPP lane-swap within 16-lane rows
template<int C>
__device__ __forceinline__ float dppf(float x) {
    union { float f; int i; } a, r;
    a.f = x;
    r.i = __builtin_amdgcn_update_dpp(a.i, a.i, C, 0xF, 0xF, false);
    return r.f;
}
__device__ __forceinline__ float redmax16(float x) {
    x = fmaxf(x, dppf<0xB1>(x));    // xor 1
    x = fmaxf(x, dppf<0x4E>(x));    // xor 2
    x = fmaxf(x, dppf<0x141>(x));   // row_half_mirror -> xor 4
    x = fmaxf(x, dppf<0x140>(x));   // row_mirror      -> xor 8
    return x;
}
__device__ __forceinline__ float redsum16(float x) {
    x += dppf<0xB1>(x);
    x += dppf<0x4E>(x);
    x += dppf<0x141>(x);
    x += dppf<0x140>(x);
    return x;
}

// q pre-scaled by 1/sqrt(64) * log2(e) so softmax runs in exp2 domain
#define QSCALE 0.18033688011112042f

// ============ fp32 [rows][1024] -> bf16 tile-major pre-swizzled layout ============
// Element (m,k): tile (mt=m>>7, kt=k>>6), r=m&127, seg=(k&63)>>3, e=k&7.
// byte off = (mt*16+kt)*16384 + r*128 + ((seg ^ (r&7))<<4) + e*2.
// This equals the LDS image gemm_lds wants, so staging is a linear DMA copy.
__global__ __launch_bounds__(256) void cvt_tile(
    const float* __restrict__ src, u16* __restrict__ dst, int ngroups)
{
    const int gid = blockIdx.x * 256 + threadIdx.x;
    if (gid >= ngroups) return;
    const int m = gid >> 7, s = gid & 127;          // s: 8-elem group within row
    const int kt = s >> 3, seg = s & 7;
    const float4 a0 = *(const float4*)&src[m * 1024 + s * 8];
    const float4 a1 = *(const float4*)&src[m * 1024 + s * 8 + 4];
    uint4 t;
    t.x = pkbf(a0.x, a0.y); t.y = pkbf(a0.z, a0.w);
    t.z = pkbf(a1.x, a1.y); t.w = pkbf(a1.z, a1.w);
    const int mt = m >> 7, r = m & 127;
    char* d = (char*)dst + ((size_t)(mt * 16 + kt)) * 16384
              + r * 128 + ((seg ^ (r & 7)) << 4);
    *(uint4*)d = t;
}

// ================= MFMA GEMM via global_load_lds (m97 structure) =================
// A, B: bf16 tile-major pre-swizzled (cvt_tile layout). 128x128 tile, BK=64,
// 4 waves (2x2), 4x4 frags mfma_f32_16x16x32_bf16, explicit LDS double-buffer.
// EPI 0: qkv epilogue (q,k [B,H,T,D], q scaled QSCALE; v transposed [B,H,D,T])
// EPI 1: proj epilogue (fp32 out + bias)
template<int EPI>
__global__ __launch_bounds__(256, 2) void gemm_lds(
    const char* __restrict__ At, const char* __restrict__ Bt,
    const float* __restrict__ bias,
    u16* __restrict__ q, u16* __restrict__ k, u16* __restrict__ vt,
    float* __restrict__ outF)
{
    __shared__ __align__(16) char AsB[2][16384];
    __shared__ __align__(16) char BsB[2][16384];
    const int tid = threadIdx.x;
    const int l = tid & 63, li = l & 15, lg = l >> 4;
    const int w = tid >> 6, wm = w >> 1, wn = w & 1;
    const int m0 = blockIdx.y * 128, n0 = blockIdx.x * 128;
    const char* Ab = At + (size_t)blockIdx.y * (16 * 16384);
    const char* Bb = Bt + (size_t)blockIdx.x * (16 * 16384);

    f32x4 acc[4][4];
    #pragma unroll
    for (int i = 0; i < 4; ++i)
        #pragma unroll
        for (int j = 0; j < 4; ++j) acc[i][j] = (f32x4){0.f, 0.f, 0.f, 0.f};

    // ---- prologue: DMA tile 0 into buf 0 ----
    #pragma unroll
    for (int i = 0; i < 4; ++i) {
        gll16(Ab + w * 4096 + i * 1024 + l * 16, &AsB[0][w * 4096 + i * 1024]);
        gll16(Bb + w * 4096 + i * 1024 + l * 16, &BsB[0][w * 4096 + i * 1024]);
    }
    asm volatile("s_waitcnt vmcnt(0)" ::: "memory");
    __syncthreads();

    for (int kt = 0; kt < 16; ++kt) {
        const int cur = kt & 1;
        // ---- DMA next tile into the other buffer (in flight under MFMA) ----
        if (kt + 1 < 16) {
            const char* An = Ab + (kt + 1) * 16384;
            const char* Bn = Bb + (kt + 1) * 16384;
            #pragma unroll
            for (int i = 0; i < 4; ++i) {
                gll16(An + w * 4096 + i * 1024 + l * 16, &AsB[cur ^ 1][w * 4096 + i * 1024]);
                gll16(Bn + w * 4096 + i * 1024 + l * 16, &BsB[cur ^ 1][w * 4096 + i * 1024]);
            }
        }
        // ---- compute from current buffer ----
        #pragma unroll
        for (int kc = 0; kc < 2; ++kc) {
            const int key = ((kc * 4 + lg) ^ (li & 7)) << 4;
            bf16x8 a[4], b[4];
            #pragma unroll
            for (int f = 0; f < 4; ++f)
                a[f] = *(const bf16x8*)&AsB[cur][(wm * 64 + f * 16 + li) * 128 + key];
            #pragma unroll
            for (int f = 0; f < 4; ++f)
                b[f] = *(const bf16x8*)&BsB[cur][(wn * 64 + f * 16 + li) * 128 + key];
            #pragma unroll
            for (int mi = 0; mi < 4; ++mi)
                #pragma unroll
                for (int ni = 0; ni < 4; ++ni)
                    acc[mi][ni] = __builtin_amdgcn_mfma_f32_16x16x32_bf16(a[mi], b[ni], acc[mi][ni], 0, 0, 0);
        }
        asm volatile("s_waitcnt vmcnt(0)" ::: "memory");
        __syncthreads();
    }

    const int mb = m0 + wm * 64;
    const int nb0 = n0 + wn * 64;
    if constexpr (EPI == 0) {
        const int part = n0 >> 10;
        if (part < 2) {
            u16* dst = (part == 0) ? q : k;
            const float scl = (part == 0) ? QSCALE : 1.0f;
            #pragma unroll
            for (int mi = 0; mi < 4; ++mi)
                #pragma unroll
                for (int r = 0; r < 4; ++r) {
                    const int m = mb + mi * 16 + lg * 4 + r;
                    const int bb = m >> 11, t = m & 2047;
                    #pragma unroll
                    for (int ni = 0; ni < 4; ++ni) {
                        const int n = nb0 + ni * 16 + li;
                        const int c = n & 1023;
                        const int h = c >> 6, d = c & 63;
                        const float val = (acc[mi][ni][r] + bias[n]) * scl;
                        dst[(((bb << 4) + h) * T_ + t) * DH + d] = f2bf(val);
                    }
                }
        } else {
            // V transposed: vt[((b*16+h)*64 + d)*2048 + t]; 4 consecutive t per store
            #pragma unroll
            for (int mi = 0; mi < 4; ++mi) {
                const int m = mb + mi * 16 + lg * 4;
                const int bb = m >> 11, t0 = m & 2047;
                #pragma unroll
                for (int ni = 0; ni < 4; ++ni) {
                    const int n = nb0 + ni * 16 + li;
                    const int c = n & 1023;
                    const int h = c >> 6, d = c & 63;
                    const float bz = bias[n];
                    u32 w0 = pkbf(acc[mi][ni][0] + bz, acc[mi][ni][1] + bz);
                    u32 w1 = pkbf(acc[mi][ni][2] + bz, acc[mi][ni][3] + bz);
                    *(uint2*)&vt[(((bb << 4) + h) * 64 + d) * (size_t)T_ + t0] = make_uint2(w0, w1);
                }
            }
        }
    } else {
        #pragma unroll
        for (int mi = 0; mi < 4; ++mi)
            #pragma unroll
            for (int r = 0; r < 4; ++r) {
                const int m = mb + mi * 16 + lg * 4 + r;
                #pragma unroll
                for (int ni = 0; ni < 4; ++ni) {
                    const int n = nb0 + ni * 16 + li;
                    outF[m * 1024 + n] = acc[mi][ni][r] + bias[n];
                }
            }
    }
}

// ---------------- MFMA flash attention (R5 structure + validated micro-opts) ----------------
// 512 threads (8 waves), Q-tile 128. Grid (32 bh, 8 pairs): q-tiles {pr, 15-pr} -> 34 KV-64
// tiles per block, uniform. K LDS [t][d], V LDS [d][t] (from pre-transposed Vt), 16B-seg
// XOR swizzle, double-buffered, 1 barrier/tile. exp2 softmax, deferred l-sum, setprio.
// Y written in the cvt_tile tiled-swizzled layout so proj can stage it via global_load_lds.
__global__ __launch_bounds__(512, 2) void flash_attn(
    const u16* __restrict__ Q, const u16* __restrict__ K,
    const u16* __restrict__ Vt, char* __restrict__ Yt)
{
    __shared__ __align__(16) char KsB[2][8192];
    __shared__ __align__(16) char VsB[2][8192];
    __shared__ __align__(16) char PsB[8][2048];

    const int bh = blockIdx.x;
    const int pr = blockIdx.y;
    const int tid = threadIdx.x;
    const int w  = tid >> 6;
    const int l  = tid & 63;
    const int li = l & 15, lg = l >> 4;
    const u16* Qb = Q  + (size_t)bh * (T_ * DH);
    const u16* Kb = K  + (size_t)bh * (T_ * DH);
    const u16* Vb = Vt + (size_t)bh * (T_ * DH);   // rows (d) of length T_
    const int srow = tid >> 3;   // 0..63
    const int sseg = tid & 7;    // 16B segment
    char* Pw = PsB[w];
    const int b = bh >> 4, h = bh & 15;
    const int skey = (srow & 7) << 4;
    const int rdkey = (li & 7) << 4;

    #pragma unroll
    for (int ph = 0; ph < 2; ++ph) {
        const int qt = ph ? (15 - pr) : pr;
        const int wq0 = qt * 128 + w * 16;
        const int nkv = 2 * qt + 2;

        bf16x8 qa[2];
        {
            const int qrow = wq0 + li;
            qa[0] = *(const bf16x8*)(Qb + qrow * 64 + 0  + lg * 8);
            qa[1] = *(const bf16x8*)(Qb + qrow * 64 + 32 + lg * 8);
        }
        f32x4 o[4];
        #pragma unroll
        for (int nb = 0; nb < 4; ++nb) o[nb] = (f32x4){0.f, 0.f, 0.f, 0.f};
        float m_r[4], l_r[4];
        #pragma unroll
        for (int r = 0; r < 4; ++r) { m_r[r] = -INFINITY; l_r[r] = 0.f; }

        uint4 kr, vr;
        // ---- prologue: stage tile 0 into buf 0 ----
        kr = *(const uint4*)(Kb + srow * 64 + sseg * 8);
        vr = *(const uint4*)(Vb + srow * (size_t)T_ + sseg * 8);
        *(uint4*)&KsB[0][srow * 128 + ((sseg << 4) ^ skey)] = kr;
        *(uint4*)&VsB[0][srow * 128 + ((sseg << 4) ^ skey)] = vr;
        __syncthreads();

        for (int j = 0; j < nkv; ++j) {
            const int cur = j & 1;
            const bool has_next = (j + 1 < nkv);
            const bool full_mask = (j * 64 >= wq0 + 16);
            // ---- issue next tile's global loads ----
            if (has_next) {
                kr = *(const uint4*)(Kb + ((j + 1) * 64 + srow) * 64 + sseg * 8);
                vr = *(const uint4*)(Vb + srow * (size_t)T_ + (j + 1) * 64 + sseg * 8);
            }
            f32x4 s[4];
            if (!full_mask) {
                // ---- S = Q.K^T ----
                const char* Kc = KsB[cur];
                __builtin_amdgcn_s_setprio(1);
                #pragma unroll
                for (int f = 0; f < 4; ++f) {
                    s[f] = (f32x4){0.f, 0.f, 0.f, 0.f};
                    #pragma unroll
                    for (int c = 0; c < 2; ++c) {
                        bf16x8 kb = *(const bf16x8*)&Kc[(f * 16 + li) * 128 + ((c * 64 + lg * 16) ^ rdkey)];
                        s[f] = __builtin_amdgcn_mfma_f32_16x16x32_bf16(qa[c], kb, s[f], 0, 0, 0);
                    }
                }
                __builtin_amdgcn_s_setprio(0);
                if ((j + 1) * 64 > wq0) {   // diagonal tile for this wave
                    #pragma unroll
                    for (int f = 0; f < 4; ++f)
                        #pragma unroll
                        for (int r = 0; r < 4; ++r)
                            if (j * 64 + f * 16 + li > wq0 + lg * 4 + r) s[f][r] = -INFINITY;
                }
                // ---- online softmax (exp2 domain), l-sum deferred ----
                #pragma unroll
                for (int r = 0; r < 4; ++r) {
                    float tm = fmaxf(fmaxf(s[0][r], s[1][r]), fmaxf(s[2][r], s[3][r]));
                    tm = redmax16(tm);
                    const float mnew = fmaxf(m_r[r], tm);
                    const float corr = exp2f(m_r[r] - mnew);
                    m_r[r] = mnew;
                    float a = 0.f;
                    #pragma unroll
                    for (int f = 0; f < 4; ++f) {
                        const float p = exp2f(s[f][r] - mnew);
                        s[f][r] = p;
                        a += p;
                    }
                    l_r[r] = l_r[r] * corr + a;
                    #pragma unroll
                    for (int nb = 0; nb < 4; ++nb) o[nb][r] *= corr;
                }
                // ---- P -> per-wave LDS (cvt_pk) ----
                #pragma unroll
                for (int r = 0; r < 4; ++r) {
                    const int row = lg * 4 + r;
                    const int rkey = (row & 7) << 4;
                    const u32 pk0 = pkbf(s[0][r], s[1][r]);
                    const u32 pk1 = pkbf(s[2][r], s[3][r]);
                    *(u16*)&Pw[row * 128 + (((     li) * 2) ^ rkey)] = (u16)pk0;
                    *(u16*)&Pw[row * 128 + (((16 + li) * 2) ^ rkey)] = (u16)(pk0 >> 16);
                    *(u16*)&Pw[row * 128 + (((32 + li) * 2) ^ rkey)] = (u16)pk1;
                    *(u16*)&Pw[row * 128 + (((48 + li) * 2) ^ rkey)] = (u16)(pk1 >> 16);
                }
            }
            // ---- write prefetched K/V into the other buffer ----
            if (has_next) {
                *(uint4*)&KsB[cur ^ 1][srow * 128 + ((sseg << 4) ^ skey)] = kr;
                *(uint4*)&VsB[cur ^ 1][srow * 128 + ((sseg << 4) ^ skey)] = vr;
            }
            // ---- O += P @ V ----
            if (!full_mask) {
                const char* Vc = VsB[cur];
                __builtin_amdgcn_s_setprio(1);
                #pragma unroll
                for (int c = 0; c < 2; ++c) {
                    bf16x8 pa = *(const bf16x8*)&Pw[li * 128 + ((c * 64 + lg * 16) ^ rdkey)];
                    #pragma unroll
                    for (int nb = 0; nb < 4; ++nb) {
                        bf16x8 vb = *(const bf16x8*)&Vc[(nb * 16 + li) * 128 + ((c * 64 + lg * 16) ^ rdkey)];
                        o[nb] = __builtin_amdgcn_mfma_f32_16x16x32_bf16(pa, vb, o[nb], 0, 0, 0);
                    }
                }
                __builtin_amdgcn_s_setprio(0);
            }
            __syncthreads();
        }

        // ---- epilogue: reduce l, normalize, write Y in tiled-swizzled layout ----
        // Y matrix row = b*2048 + (qt*128 + r128)  ->  mt = b*16 + qt ; kt = h
        const size_t ybase = ((size_t)((b * 16 + qt) * 16 + h)) * 16384;
        #pragma unroll
        for (int r = 0; r < 4; ++r) {
            const float inv = 1.0f / redsum16(l_r[r]);
            const int r128 = w * 16 + lg * 4 + r;
            const int rk = (r128 & 7) << 4;
            char* yrow = Yt + ybase + r128 * 128;
            #pragma unroll
            for (int nb = 0; nb < 4; ++nb) {
                const int seg = nb * 2 + (li >> 3);
                *(u16*)&yrow[((seg << 4) ^ rk) + (li & 7) * 2] = f2bf(o[nb][r] * inv);
            }
        }
    }
}

extern "C" void kernel_launch(void* const* d_in, const int* in_sizes, int n_in,
                              void* d_out, int out_size, void* d_ws, size_t ws_size,
                              hipStream_t stream) {
    const float* x      = (const float*)d_in[0];
    const float* W_attn = (const float*)d_in[1];
    const float* b_attn = (const float*)d_in[2];
    const float* W_proj = (const float*)d_in[3];
    const float* b_proj = (const float*)d_in[4];
    float* out = (float*)d_out;

    char* ws = (char*)d_ws;
    u16* q   = (u16*)ws;                          // [B,H,T,D] bf16, 8 MB
    u16* k   = (u16*)(ws + (8u << 20));           // [B,H,T,D] 8 MB
    u16* vt  = (u16*)(ws + (16u << 20));          // [B,H,D,T] 8 MB
    char* xb = ws + (24u << 20);                  // x tiled bf16 8 MB; REUSED as Yt after qkv
    char* wab = ws + (32u << 20);                 // W_attn tiled bf16 6 MB
    char* wpb = ws + (38u << 20);                 // W_proj tiled bf16 2 MB

    cvt_tile<<<2048, 256, 0, stream>>>(x,      (u16*)xb,  4096 * 128);
    cvt_tile<<<1536, 256, 0, stream>>>(W_attn, (u16*)wab, 3072 * 128);
    cvt_tile<<< 512, 256, 0, stream>>>(W_proj, (u16*)wpb, 1024 * 128);
    gemm_lds<0><<<dim3(24, 32), 256, 0, stream>>>(xb, wab, b_attn, q, k, vt, nullptr);
    flash_attn<<<dim3(32, 8), 512, 0, stream>>>(q, k, vt, xb /* Yt */);
    gemm_lds<1><<<dim3(8, 32), 256, 0, stream>>>(xb /* Yt */, wpb, b_proj,
                                                 nullptr, nullptr, nullptr, out);
}

// Round 9
// 131.915 us; speedup vs baseline: 1.6122x; 1.0738x over previous
//
#include <hip/hip_runtime.h>

typedef unsigned int u32;
typedef unsigned short u16;
typedef __attribute__((ext_vector_type(8))) short bf16x8;
typedef __attribute__((ext_vector_type(4))) float f32x4;

#define T_ 2048
#define HEADS 16
#define DH 64
#define NQ (2 * HEADS * T_ * DH)  // 4194304 elems per tensor

__device__ __forceinline__ u16 f2bf(float f) {
    union { float f; u32 u; } x; x.f = f;
    return (u16)((x.u + 0x7fffu + ((x.u >> 16) & 1u)) >> 16);
}
// packed f32x2 -> bf16x2 (RNE), single HW instruction
__device__ __forceinline__ u32 pkbf(float lo, float hi) {
    u32 r;
    asm("v_cvt_pk_bf16_f32 %0, %1, %2" : "=v"(r) : "v"(lo), "v"(hi));
    return r;
}
// async global->LDS, 16B per lane: LDS dest = wave-uniform base + lane*16
__device__ __forceinline__ void gll16(const void* g, void* l) {
    __builtin_amdgcn_global_load_lds(
        (const __attribute__((address_space(1))) void*)g,
        (__attribute__((address_space(3))) void*)l, 16, 0, 0);
}
// DPP lane-swap within 16-lane rows
template<int C>
__device__ __forceinline__ float dppf(float x) {
    union { float f; int i; } a, r;
    a.f = x;
    r.i = __builtin_amdgcn_update_dpp(a.i, a.i, C, 0xF, 0xF, false);
    return r.f;
}
__device__ __forceinline__ float redmax16(float x) {
    x = fmaxf(x, dppf<0xB1>(x));    // xor 1
    x = fmaxf(x, dppf<0x4E>(x));    // xor 2
    x = fmaxf(x, dppf<0x141>(x));   // row_half_mirror -> xor 4
    x = fmaxf(x, dppf<0x140>(x));   // row_mirror      -> xor 8
    return x;
}
__device__ __forceinline__ float redsum16(float x) {
    x += dppf<0xB1>(x);
    x += dppf<0x4E>(x);
    x += dppf<0x141>(x);
    x += dppf<0x140>(x);
    return x;
}

// q pre-scaled by 1/sqrt(64) * log2(e) so softmax runs in exp2 domain
#define QSCALE 0.18033688011112042f
#define DEFER_THR 8.0f

// ============ fused fp32 [rows][1024] -> bf16 tile-major pre-swizzled (3 tensors) ============
// Element (m,k): tile (mt=m>>7, kt=k>>6), r=m&127, seg=(k&63)>>3, e=k&7.
// byte off = (mt*16+kt)*16384 + r*128 + ((seg ^ (r&7))<<4) + e*2.
#define NG_X  (4096 * 128)
#define NG_WA (3072 * 128)
__global__ __launch_bounds__(256) void cvt_all(
    const float* __restrict__ x, const float* __restrict__ wa,
    const float* __restrict__ wp,
    u16* __restrict__ dx, u16* __restrict__ dwa, u16* __restrict__ dwp)
{
    int gid = blockIdx.x * 256 + threadIdx.x;
    const float* src; u16* dst;
    if (gid < NG_X)                { src = x;  dst = dx; }
    else if (gid < NG_X + NG_WA)   { src = wa; dst = dwa; gid -= NG_X; }
    else                           { src = wp; dst = dwp; gid -= NG_X + NG_WA; }
    const int m = gid >> 7, s = gid & 127;          // s: 8-elem group within row
    const int kt = s >> 3, seg = s & 7;
    const float4 a0 = *(const float4*)&src[m * 1024 + s * 8];
    const float4 a1 = *(const float4*)&src[m * 1024 + s * 8 + 4];
    uint4 t;
    t.x = pkbf(a0.x, a0.y); t.y = pkbf(a0.z, a0.w);
    t.z = pkbf(a1.x, a1.y); t.w = pkbf(a1.z, a1.w);
    const int mt = m >> 7, r = m & 127;
    char* d = (char*)dst + ((size_t)(mt * 16 + kt)) * 16384
              + r * 128 + ((seg ^ (r & 7)) << 4);
    *(uint4*)d = t;
}

// ================= MFMA GEMM via global_load_lds (m97 structure) =================
// A, B: bf16 tile-major pre-swizzled (cvt layout). 128x128 tile, BK=64,
// 4 waves (2x2), 4x4 frags mfma_f32_16x16x32_bf16, explicit LDS double-buffer.
// EPI 0: qkv epilogue (q,k [B,H,T,D], q scaled QSCALE; v transposed [B,H,D,T])
// EPI 1: proj epilogue (fp32 out + bias)
template<int EPI>
__global__ __launch_bounds__(256, 2) void gemm_lds(
    const char* __restrict__ At, const char* __restrict__ Bt,
    const float* __restrict__ bias,
    u16* __restrict__ q, u16* __restrict__ k, u16* __restrict__ vt,
    float* __restrict__ outF)
{
    __shared__ __align__(16) char AsB[2][16384];
    __shared__ __align__(16) char BsB[2][16384];
    const int tid = threadIdx.x;
    const int l = tid & 63, li = l & 15, lg = l >> 4;
    const int w = tid >> 6, wm = w >> 1, wn = w & 1;
    const int m0 = blockIdx.y * 128, n0 = blockIdx.x * 128;
    const char* Ab = At + (size_t)blockIdx.y * (16 * 16384);
    const char* Bb = Bt + (size_t)blockIdx.x * (16 * 16384);

    f32x4 acc[4][4];
    #pragma unroll
    for (int i = 0; i < 4; ++i)
        #pragma unroll
        for (int j = 0; j < 4; ++j) acc[i][j] = (f32x4){0.f, 0.f, 0.f, 0.f};

    // ---- prologue: DMA tile 0 into buf 0 ----
    #pragma unroll
    for (int i = 0; i < 4; ++i) {
        gll16(Ab + w * 4096 + i * 1024 + l * 16, &AsB[0][w * 4096 + i * 1024]);
        gll16(Bb + w * 4096 + i * 1024 + l * 16, &BsB[0][w * 4096 + i * 1024]);
    }
    asm volatile("s_waitcnt vmcnt(0)" ::: "memory");
    __syncthreads();

    for (int kt = 0; kt < 16; ++kt) {
        const int cur = kt & 1;
        if (kt + 1 < 16) {
            const char* An = Ab + (kt + 1) * 16384;
            const char* Bn = Bb + (kt + 1) * 16384;
            #pragma unroll
            for (int i = 0; i < 4; ++i) {
                gll16(An + w * 4096 + i * 1024 + l * 16, &AsB[cur ^ 1][w * 4096 + i * 1024]);
                gll16(Bn + w * 4096 + i * 1024 + l * 16, &BsB[cur ^ 1][w * 4096 + i * 1024]);
            }
        }
        #pragma unroll
        for (int kc = 0; kc < 2; ++kc) {
            const int key = ((kc * 4 + lg) ^ (li & 7)) << 4;
            bf16x8 a[4], b[4];
            #pragma unroll
            for (int f = 0; f < 4; ++f)
                a[f] = *(const bf16x8*)&AsB[cur][(wm * 64 + f * 16 + li) * 128 + key];
            #pragma unroll
            for (int f = 0; f < 4; ++f)
                b[f] = *(const bf16x8*)&BsB[cur][(wn * 64 + f * 16 + li) * 128 + key];
            #pragma unroll
            for (int mi = 0; mi < 4; ++mi)
                #pragma unroll
                for (int ni = 0; ni < 4; ++ni)
                    acc[mi][ni] = __builtin_amdgcn_mfma_f32_16x16x32_bf16(a[mi], b[ni], acc[mi][ni], 0, 0, 0);
        }
        asm volatile("s_waitcnt vmcnt(0)" ::: "memory");
        __syncthreads();
    }

    const int mb = m0 + wm * 64;
    const int nb0 = n0 + wn * 64;
    if constexpr (EPI == 0) {
        const int part = n0 >> 10;
        if (part < 2) {
            u16* dst = (part == 0) ? q : k;
            const float scl = (part == 0) ? QSCALE : 1.0f;
            #pragma unroll
            for (int mi = 0; mi < 4; ++mi)
                #pragma unroll
                for (int r = 0; r < 4; ++r) {
                    const int m = mb + mi * 16 + lg * 4 + r;
                    const int bb = m >> 11, t = m & 2047;
                    #pragma unroll
                    for (int ni = 0; ni < 4; ++ni) {
                        const int n = nb0 + ni * 16 + li;
                        const int c = n & 1023;
                        const int h = c >> 6, d = c & 63;
                        const float val = (acc[mi][ni][r] + bias[n]) * scl;
                        dst[(((bb << 4) + h) * T_ + t) * DH + d] = f2bf(val);
                    }
                }
        } else {
            // V transposed: vt[((b*16+h)*64 + d)*2048 + t]
            #pragma unroll
            for (int mi = 0; mi < 4; ++mi) {
                const int m = mb + mi * 16 + lg * 4;
                const int bb = m >> 11, t0 = m & 2047;
                #pragma unroll
                for (int ni = 0; ni < 4; ++ni) {
                    const int n = nb0 + ni * 16 + li;
                    const int c = n & 1023;
                    const int h = c >> 6, d = c & 63;
                    const float bz = bias[n];
                    u32 w0 = pkbf(acc[mi][ni][0] + bz, acc[mi][ni][1] + bz);
                    u32 w1 = pkbf(acc[mi][ni][2] + bz, acc[mi][ni][3] + bz);
                    *(uint2*)&vt[(((bb << 4) + h) * 64 + d) * (size_t)T_ + t0] = make_uint2(w0, w1);
                }
            }
        }
    } else {
        #pragma unroll
        for (int mi = 0; mi < 4; ++mi)
            #pragma unroll
            for (int r = 0; r < 4; ++r) {
                const int m = mb + mi * 16 + lg * 4 + r;
                #pragma unroll
                for (int ni = 0; ni < 4; ++ni) {
                    const int n = nb0 + ni * 16 + li;
                    outF[m * 1024 + n] = acc[mi][ni][r] + bias[n];
                }
            }
    }
}

// ---------------- MFMA flash attention v9 ----------------
// 256 threads (4 waves), Q-tile 64 (wave w owns rows qt*64+w*16..+16). KV tile 64.
// Grid (32 bh, 16 pr): block does q-tiles {pr, 31-pr} -> 33 KV tiles, uniform.
// 512 blocks -> 2 independent barrier domains per CU. LDS 40KB, dbuf K/V, per-wave P.
// exp2 softmax + DPP reductions + deferred l-sum + defer-max (THR=8) + setprio.
// Y written in cvt tiled-swizzled layout for proj's global_load_lds staging.
__global__ __launch_bounds__(256, 2) void flash_attn(
    const u16* __restrict__ Q, const u16* __restrict__ K,
    const u16* __restrict__ Vt, char* __restrict__ Yt)
{
    __shared__ __align__(16) char KsB[2][8192];
    __shared__ __align__(16) char VsB[2][8192];
    __shared__ __align__(16) char PsB[4][2048];

    const int bh = blockIdx.x;
    const int pr = blockIdx.y;
    const int tid = threadIdx.x;
    const int w  = tid >> 6;
    const int l  = tid & 63;
    const int li = l & 15, lg = l >> 4;
    const u16* Qb = Q  + (size_t)bh * (T_ * DH);
    const u16* Kb = K  + (size_t)bh * (T_ * DH);
    const u16* Vb = Vt + (size_t)bh * (T_ * DH);   // rows (d) of length T_
    const int srow = tid >> 2;   // 0..63
    const int sseg = tid & 3;    // first 16B segment (second is +4)
    char* Pw = PsB[w];
    const int b = bh >> 4, h = bh & 15;
    const int skey = (srow & 7) << 4;
    const int rdkey = (li & 7) << 4;

    #pragma unroll
    for (int ph = 0; ph < 2; ++ph) {
        const int qt = ph ? (31 - pr) : pr;
        const int wq0 = qt * 64 + w * 16;
        const int nkv = qt + 1;

        bf16x8 qa[2];
        {
            const int qrow = wq0 + li;
            qa[0] = *(const bf16x8*)(Qb + qrow * 64 + 0  + lg * 8);
            qa[1] = *(const bf16x8*)(Qb + qrow * 64 + 32 + lg * 8);
        }
        f32x4 o[4];
        #pragma unroll
        for (int nb = 0; nb < 4; ++nb) o[nb] = (f32x4){0.f, 0.f, 0.f, 0.f};
        float m_r[4], l_r[4];
        #pragma unroll
        for (int r = 0; r < 4; ++r) { m_r[r] = -INFINITY; l_r[r] = 0.f; }

        uint4 kr0, kr1, vr0, vr1;
        // ---- prologue: stage tile 0 into buf 0 ----
        kr0 = *(const uint4*)(Kb + srow * 64 + sseg * 8);
        kr1 = *(const uint4*)(Kb + srow * 64 + (sseg + 4) * 8);
        vr0 = *(const uint4*)(Vb + (size_t)srow * T_ + sseg * 8);
        vr1 = *(const uint4*)(Vb + (size_t)srow * T_ + (sseg + 4) * 8);
        // safe: first phase has no prior LDS use; second phase's loop ended in syncthreads
        *(uint4*)&KsB[0][srow * 128 + ((sseg       << 4) ^ skey)] = kr0;
        *(uint4*)&KsB[0][srow * 128 + (((sseg + 4) << 4) ^ skey)] = kr1;
        *(uint4*)&VsB[0][srow * 128 + ((sseg       << 4) ^ skey)] = vr0;
        *(uint4*)&VsB[0][srow * 128 + (((sseg + 4) << 4) ^ skey)] = vr1;
        __syncthreads();

        for (int j = 0; j < nkv; ++j) {
            const int cur = j & 1;
            const bool has_next = (j + 1 < nkv);
            // ---- issue next tile's global loads (latency hides under compute) ----
            if (has_next) {
                const int t0 = (j + 1) * 64;
                kr0 = *(const uint4*)(Kb + (t0 + srow) * 64 + sseg * 8);
                kr1 = *(const uint4*)(Kb + (t0 + srow) * 64 + (sseg + 4) * 8);
                vr0 = *(const uint4*)(Vb + (size_t)srow * T_ + t0 + sseg * 8);
                vr1 = *(const uint4*)(Vb + (size_t)srow * T_ + t0 + (sseg + 4) * 8);
            }
            // ---- S = Q.K^T ----
            const char* Kc = KsB[cur];
            f32x4 s[4];
            __builtin_amdgcn_s_setprio(1);
            #pragma unroll
            for (int f = 0; f < 4; ++f) {
                s[f] = (f32x4){0.f, 0.f, 0.f, 0.f};
                #pragma unroll
                for (int c = 0; c < 2; ++c) {
                    bf16x8 kb = *(const bf16x8*)&Kc[(f * 16 + li) * 128 + ((c * 64 + lg * 16) ^ rdkey)];
                    s[f] = __builtin_amdgcn_mfma_f32_16x16x32_bf16(qa[c], kb, s[f], 0, 0, 0);
                }
            }
            __builtin_amdgcn_s_setprio(0);
            // ---- causal mask on diagonal tile (only j==qt can cross) ----
            if ((j + 1) * 64 > wq0) {
                #pragma unroll
                for (int f = 0; f < 4; ++f)
                    #pragma unroll
                    for (int r = 0; r < 4; ++r)
                        if (j * 64 + f * 16 + li > wq0 + lg * 4 + r) s[f][r] = -INFINITY;
            }
            // ---- online softmax (exp2), defer-max, deferred l-sum ----
            float tm[4];
            #pragma unroll
            for (int r = 0; r < 4; ++r) {
                float t = fmaxf(fmaxf(s[0][r], s[1][r]), fmaxf(s[2][r], s[3][r]));
                tm[r] = redmax16(t);
            }
            const bool skip = __all((tm[0] <= m_r[0] + DEFER_THR) &
                                    (tm[1] <= m_r[1] + DEFER_THR) &
                                    (tm[2] <= m_r[2] + DEFER_THR) &
                                    (tm[3] <= m_r[3] + DEFER_THR));
            if (skip) {
                #pragma unroll
                for (int r = 0; r < 4; ++r) {
                    float a = 0.f;
                    #pragma unroll
                    for (int f = 0; f < 4; ++f) {
                        const float p = exp2f(s[f][r] - m_r[r]);
                        s[f][r] = p;
                        a += p;
                    }
                    l_r[r] += a;
                }
            } else {
                #pragma unroll
                for (int r = 0; r < 4; ++r) {
                    const float mnew = fmaxf(m_r[r], tm[r]);
                    const float corr = exp2f(m_r[r] - mnew);
                    m_r[r] = mnew;
                    float a = 0.f;
                    #pragma unroll
                    for (int f = 0; f < 4; ++f) {
                        const float p = exp2f(s[f][r] - mnew);
                        s[f][r] = p;
                        a += p;
                    }
                    l_r[r] = l_r[r] * corr + a;
                    #pragma unroll
                    for (int nb = 0; nb < 4; ++nb) o[nb][r] *= corr;
                }
            }
            // ---- P -> per-wave LDS (cvt_pk) ----
            #pragma unroll
            for (int r = 0; r < 4; ++r) {
                const int row = lg * 4 + r;
                const int rkey = (row & 7) << 4;
                const u32 pk0 = pkbf(s[0][r], s[1][r]);
                const u32 pk1 = pkbf(s[2][r], s[3][r]);
                *(u16*)&Pw[row * 128 + (((     li) * 2) ^ rkey)] = (u16)pk0;
                *(u16*)&Pw[row * 128 + (((16 + li) * 2) ^ rkey)] = (u16)(pk0 >> 16);
                *(u16*)&Pw[row * 128 + (((32 + li) * 2) ^ rkey)] = (u16)pk1;
                *(u16*)&Pw[row * 128 + (((48 + li) * 2) ^ rkey)] = (u16)(pk1 >> 16);
            }
            // ---- write prefetched K/V into the other buffer ----
            if (has_next) {
                *(uint4*)&KsB[cur ^ 1][srow * 128 + ((sseg       << 4) ^ skey)] = kr0;
                *(uint4*)&KsB[cur ^ 1][srow * 128 + (((sseg + 4) << 4) ^ skey)] = kr1;
                *(uint4*)&VsB[cur ^ 1][srow * 128 + ((sseg       << 4) ^ skey)] = vr0;
                *(uint4*)&VsB[cur ^ 1][srow * 128 + (((sseg + 4) << 4) ^ skey)] = vr1;
            }
            // ---- O += P @ V ----
            const char* Vc = VsB[cur];
            __builtin_amdgcn_s_setprio(1);
            #pragma unroll
            for (int c = 0; c < 2; ++c) {
                bf16x8 pa = *(const bf16x8*)&Pw[li * 128 + ((c * 64 + lg * 16) ^ rdkey)];
                #pragma unroll
                for (int nb = 0; nb < 4; ++nb) {
                    bf16x8 vb = *(const bf16x8*)&Vc[(nb * 16 + li) * 128 + ((c * 64 + lg * 16) ^ rdkey)];
                    o[nb] = __builtin_amdgcn_mfma_f32_16x16x32_bf16(pa, vb, o[nb], 0, 0, 0);
                }
            }
            __builtin_amdgcn_s_setprio(0);
            __syncthreads();
        }

        // ---- epilogue: reduce l, normalize, write Y in tiled-swizzled layout ----
        // global Y row = b*2048 + qt*64 + local  ->  mt = b*16 + (qt>>1),
        // r128 = (qt&1)*64 + w*16 + lg*4 + r ; column tile = h
        const size_t ybase = ((size_t)((b * 16 + (qt >> 1)) * 16 + h)) * 16384;
        #pragma unroll
        for (int r = 0; r < 4; ++r) {
            const float inv = 1.0f / redsum16(l_r[r]);
            const int r128 = (qt & 1) * 64 + w * 16 + lg * 4 + r;
            const int rk = (r128 & 7) << 4;
            char* yrow = Yt + ybase + r128 * 128;
            #pragma unroll
            for (int nb = 0; nb < 4; ++nb) {
                const int seg = nb * 2 + (li >> 3);
                *(u16*)&yrow[((seg << 4) ^ rk) + (li & 7) * 2] = f2bf(o[nb][r] * inv);
            }
        }
    }
}

extern "C" void kernel_launch(void* const* d_in, const int* in_sizes, int n_in,
                              void* d_out, int out_size, void* d_ws, size_t ws_size,
                              hipStream_t stream) {
    const float* x      = (const float*)d_in[0];
    const float* W_attn = (const float*)d_in[1];
    const float* b_attn = (const float*)d_in[2];
    const float* W_proj = (const float*)d_in[3];
    const float* b_proj = (const float*)d_in[4];
    float* out = (float*)d_out;

    char* ws = (char*)d_ws;
    u16* q   = (u16*)ws;                          // [B,H,T,D] bf16, 8 MB
    u16* k   = (u16*)(ws + (8u << 20));           // [B,H,T,D] 8 MB
    u16* vt  = (u16*)(ws + (16u << 20));          // [B,H,D,T] 8 MB
    char* xb = ws + (24u << 20);                  // x tiled bf16 8 MB; REUSED as Yt after qkv
    char* wab = ws + (32u << 20);                 // W_attn tiled bf16 6 MB
    char* wpb = ws + (38u << 20);                 // W_proj tiled bf16 2 MB

    cvt_all<<<4096, 256, 0, stream>>>(x, W_attn, W_proj, (u16*)xb, (u16*)wab, (u16*)wpb);
    gemm_lds<0><<<dim3(24, 32), 256, 0, stream>>>(xb, wab, b_attn, q, k, vt, nullptr);
    flash_attn<<<dim3(32, 16), 256, 0, stream>>>(q, k, vt, xb /* Yt */);
    gemm_lds<1><<<dim3(8, 32), 256, 0, stream>>>(xb /* Yt */, wpb, b_proj,
                                                 nullptr, nullptr, nullptr, out);
}